// Round 2
// baseline (1856.513 us; speedup 1.0000x reference)
//
#include <hip/hip_runtime.h>
#include <hip/hip_bf16.h>

// T=256, B=4096, H=64.
// Fast path (needs ws >= 1.34 GB):
//   k1x:  xp = (relu(relu(x@Wr1+br1)@Wr2+br2)) @ Wih + b_lstm   [T*B,256] fp32,
//         gate-interleaved (unit j, gate g) -> xp[row*256 + j*4 + g]. hid never stored.
//   k2s:  serial LSTM, Whh-only matvec from LDS, 8 waves x 2 elems, no barriers
//         in the loop; h written to hs [T*B,64].
//   kcrit: parallel critic over all T*B rows of hs -> out.
// Fallback: R1 kernels (k1_mlp + k2_recur fused critic).

#define TT 256
#define BB 4096
#define HHH 64
#define TBROWS (TT * BB)

__device__ __forceinline__ float bcastf(float v, int i) {
  return __int_as_float(__builtin_amdgcn_readlane(__float_as_int(v), i));
}
__device__ __forceinline__ float fsig(float x) { return 1.f / (1.f + __expf(-x)); }
__device__ __forceinline__ float ftanhf(float x) { return 1.f - 2.f / (__expf(2.f * x) + 1.f); }

template <typename T> __device__ __forceinline__ T to_xt(float v);
template <> __device__ __forceinline__ float to_xt<float>(float v) { return v; }
template <> __device__ __forceinline__ __hip_bfloat16 to_xt<__hip_bfloat16>(float v) { return __float2bfloat16(v); }
template <typename T> __device__ __forceinline__ float from_xt(T v);
template <> __device__ __forceinline__ float from_xt<float>(float v) { return v; }
template <> __device__ __forceinline__ float from_xt<__hip_bfloat16>(__hip_bfloat16 v) { return __bfloat162float(v); }

// ================= fast path =================

// ---- k1x: MLP + Wih projection fused, writes xp only ----
__global__ __launch_bounds__(256) void k1x(const float* __restrict__ x,
                                           const float* __restrict__ Wr1,
                                           const float* __restrict__ br1,
                                           const float* __restrict__ Wr2,
                                           const float* __restrict__ br2,
                                           const float* __restrict__ Wih,
                                           const float* __restrict__ bl,
                                           float* __restrict__ xp) {
  __shared__ float sWr1[9 * 32];
  __shared__ float sbr1[32];
  __shared__ float sWr2[32 * 64];
  __shared__ float sbr2[64];
  __shared__ float sWih[64 * 256];  // [k][j*4+g]
  __shared__ float sblv[256];       // [j*4+g]
  int tid = threadIdx.x;
  for (int i = tid; i < 288; i += 256) sWr1[i] = Wr1[i];
  if (tid < 32) sbr1[tid] = br1[tid];
  for (int i = tid; i < 2048; i += 256) sWr2[i] = Wr2[i];
  if (tid < 64) sbr2[tid] = br2[tid];
  for (int i = tid; i < 64 * 256; i += 256) {
    int k = i >> 8, r = i & 255, j = r >> 2, g = r & 3;
    sWih[i] = Wih[k * 256 + g * 64 + j];
  }
  for (int i = tid; i < 256; i += 256) {
    int j = i >> 2, g = i & 3;
    sblv[i] = bl[g * 64 + j];
  }
  __syncthreads();

  int lane = tid & 63;
  int wid = tid >> 6;
  int l = lane & 31;
  long gw = (long)blockIdx.x * 4 + wid;
  long nw = (long)gridDim.x * 4;
  for (long row0 = gw * 4; row0 < TBROWS; row0 += nw * 4) {
    float xl = 0.f;
    if (lane < 36) xl = x[row0 * 9 + lane];
    float h1r[4];
#pragma unroll
    for (int r = 0; r < 4; ++r) {
      float a = sbr1[l];
#pragma unroll
      for (int k = 0; k < 9; ++k) a = fmaf(bcastf(xl, r * 9 + k), sWr1[k * 32 + l], a);
      h1r[r] = fmaxf(a, 0.f);
    }
    float h2r[4];
#pragma unroll
    for (int r = 0; r < 4; ++r) h2r[r] = sbr2[lane];
#pragma unroll
    for (int i = 0; i < 32; ++i) {
      float w = sWr2[i * 64 + lane];
#pragma unroll
      for (int r = 0; r < 4; ++r) h2r[r] = fmaf(bcastf(h1r[r], i), w, h2r[r]);
    }
#pragma unroll
    for (int r = 0; r < 4; ++r) h2r[r] = fmaxf(h2r[r], 0.f);
    // Wih projection: lane j owns unit j (4 gates = float4), 4 rows per wave
    float4 acc[4];
#pragma unroll
    for (int r = 0; r < 4; ++r) acc[r] = ((const float4*)sblv)[lane];
#pragma unroll 16
    for (int k = 0; k < 64; ++k) {
      float4 wv = ((const float4*)sWih)[k * 64 + lane];
#pragma unroll
      for (int r = 0; r < 4; ++r) {
        float s = bcastf(h2r[r], k);
        acc[r].x = fmaf(s, wv.x, acc[r].x);
        acc[r].y = fmaf(s, wv.y, acc[r].y);
        acc[r].z = fmaf(s, wv.z, acc[r].z);
        acc[r].w = fmaf(s, wv.w, acc[r].w);
      }
    }
#pragma unroll
    for (int r = 0; r < 4; ++r) ((float4*)xp)[(row0 + r) * 64 + lane] = acc[r];
  }
}

// ---- k2s: serial LSTM over T, Whh only, no in-loop barriers ----
__global__ __launch_bounds__(512) void k2s(const float* __restrict__ xp,
                                           const int* __restrict__ done,
                                           const float* __restrict__ h0,
                                           const float* __restrict__ c0,
                                           const float* __restrict__ Whh,
                                           float* __restrict__ hs) {
  __shared__ float sWhh[64 * 256];  // [k][j*4+g]
  int tid = threadIdx.x;
  for (int i = tid; i < 64 * 256; i += 512) {
    int k = i >> 8, r = i & 255, j = r >> 2, g = r & 3;
    sWhh[i] = Whh[k * 256 + g * 64 + j];
  }
  __syncthreads();

  int lane = tid & 63;
  int wid = tid >> 6;              // 0..7
  int base_b = blockIdx.x * 16 + wid * 2;

  float h[2], c[2];
#pragma unroll
  for (int e = 0; e < 2; ++e) {
    h[e] = h0[(base_b + e) * 64 + lane];
    c[e] = c0[(base_b + e) * 64 + lane];
  }
  float4 xq[2];
  int dnv[2];
#pragma unroll
  for (int e = 0; e < 2; ++e) {
    xq[e] = ((const float4*)xp)[(long)(base_b + e) * 64 + lane];
    dnv[e] = done[base_b + e];
  }

  for (int t = 0; t < TT; ++t) {
    float hm[2];
    float4 acc[2];
#pragma unroll
    for (int e = 0; e < 2; ++e) {
      float m = 1.f - (float)dnv[e];
      hm[e] = h[e] * m;
      c[e] *= m;
      acc[e] = xq[e];
    }
    if (t + 1 < TT) {
#pragma unroll
      for (int e = 0; e < 2; ++e) {
        long row = (long)(t + 1) * BB + base_b + e;
        xq[e] = ((const float4*)xp)[row * 64 + lane];
        dnv[e] = done[row];
      }
    }
#pragma unroll 16
    for (int k = 0; k < 64; ++k) {
      float4 wv = ((const float4*)sWhh)[k * 64 + lane];
#pragma unroll
      for (int e = 0; e < 2; ++e) {
        float s = bcastf(hm[e], k);
        acc[e].x = fmaf(s, wv.x, acc[e].x);
        acc[e].y = fmaf(s, wv.y, acc[e].y);
        acc[e].z = fmaf(s, wv.z, acc[e].z);
        acc[e].w = fmaf(s, wv.w, acc[e].w);
      }
    }
#pragma unroll
    for (int e = 0; e < 2; ++e) {
      float gi = fsig(acc[e].x);
      float gf = fsig(acc[e].y);
      float gg = ftanhf(acc[e].z);
      float go = fsig(acc[e].w);
      c[e] = fmaf(gf, c[e], gi * gg);
      h[e] = go * ftanhf(c[e]);
      hs[((long)t * BB + base_b + e) * 64 + lane] = h[e];
    }
  }
}

// ---- kcrit: parallel critic head over all T*B rows ----
__global__ __launch_bounds__(256) void kcrit(const float* __restrict__ hs,
                                             const float* __restrict__ Wc1,
                                             const float* __restrict__ bc1,
                                             const float* __restrict__ Wc2,
                                             const float* __restrict__ bc2,
                                             const float* __restrict__ Wc3,
                                             const float* __restrict__ bc3,
                                             float* __restrict__ out) {
  __shared__ float sWc1[64 * 16];
  __shared__ float sbc1[16];
  __shared__ float sWc2[16 * 8];
  __shared__ float sbc2[8];
  __shared__ float sWc3[8];
  __shared__ float hstage[4][4][68];
  int tid = threadIdx.x;
  for (int i = tid; i < 1024; i += 256) sWc1[i] = Wc1[i];
  if (tid < 128) sWc2[tid] = Wc2[tid];
  if (tid < 16) sbc1[tid] = bc1[tid];
  if (tid < 8) { sbc2[tid] = bc2[tid]; sWc3[tid] = Wc3[tid]; }
  __syncthreads();

  int lane = tid & 63;
  int wid = tid >> 6;
  float bc3r = bc3[0];
  int e2 = lane >> 4;
  int l16 = lane & 15;
  int gbase = lane & 48;
  long gw = (long)blockIdx.x * 4 + wid;
  long nw = (long)gridDim.x * 4;
  for (long row0 = gw * 4; row0 < TBROWS; row0 += nw * 4) {
    // lane covers row (lane>>4), units (lane&15)*4 .. +3
    float4 hv = ((const float4*)hs)[row0 * 16 + lane];
    *(float4*)&hstage[wid][e2][l16 * 4] = hv;  // wave-local staging, no barrier
    const float* hrow = &hstage[wid][e2][0];
    float a1 = sbc1[l16];
#pragma unroll
    for (int k4 = 0; k4 < 16; ++k4) {
      float4 hh = *(const float4*)(hrow + k4 * 4);
      a1 = fmaf(hh.x, sWc1[(k4 * 4 + 0) * 16 + l16], a1);
      a1 = fmaf(hh.y, sWc1[(k4 * 4 + 1) * 16 + l16], a1);
      a1 = fmaf(hh.z, sWc1[(k4 * 4 + 2) * 16 + l16], a1);
      a1 = fmaf(hh.w, sWc1[(k4 * 4 + 3) * 16 + l16], a1);
    }
    float v1 = ftanhf(a1);
    float a2 = sbc2[lane & 7];
#pragma unroll
    for (int i = 0; i < 16; ++i)
      a2 = fmaf(__shfl(v1, gbase + i), sWc2[i * 8 + (lane & 7)], a2);
    float v2 = ftanhf(a2);
    float a3 = bc3r;
#pragma unroll
    for (int i = 0; i < 8; ++i)
      a3 = fmaf(__shfl(v2, gbase + i), sWc3[i], a3);
    if (l16 == 0) out[row0 + e2] = a3;
  }
}

// ================= fallback path (R1, known-good) =================

template <typename XT>
__global__ __launch_bounds__(256) void k1_mlp(const float* __restrict__ x,
                                              const float* __restrict__ Wr1,
                                              const float* __restrict__ br1,
                                              const float* __restrict__ Wr2,
                                              const float* __restrict__ br2,
                                              XT* __restrict__ hid) {
  __shared__ float sWr1[9 * 32];
  __shared__ float sbr1[32];
  __shared__ float sWr2[32 * 64];
  __shared__ float sbr2[64];
  int tid = threadIdx.x;
  for (int i = tid; i < 288; i += 256) sWr1[i] = Wr1[i];
  if (tid < 32) sbr1[tid] = br1[tid];
  for (int i = tid; i < 2048; i += 256) sWr2[i] = Wr2[i];
  if (tid < 64) sbr2[tid] = br2[tid];
  __syncthreads();

  int lane = tid & 63;
  int wid = tid >> 6;
  int l = lane & 31;
  long gw = (long)blockIdx.x * 4 + wid;
  long nw = (long)gridDim.x * 4;
  for (long row0 = gw * 4; row0 < TBROWS; row0 += nw * 4) {
    float xl = 0.f;
    if (lane < 36) xl = x[row0 * 9 + lane];
    float h1r[4];
#pragma unroll
    for (int r = 0; r < 4; ++r) {
      float a = sbr1[l];
#pragma unroll
      for (int k = 0; k < 9; ++k) a = fmaf(bcastf(xl, r * 9 + k), sWr1[k * 32 + l], a);
      h1r[r] = fmaxf(a, 0.f);
    }
    float h2r[4];
#pragma unroll
    for (int r = 0; r < 4; ++r) h2r[r] = sbr2[lane];
#pragma unroll
    for (int i = 0; i < 32; ++i) {
      float w = sWr2[i * 64 + lane];
#pragma unroll
      for (int r = 0; r < 4; ++r) h2r[r] = fmaf(bcastf(h1r[r], i), w, h2r[r]);
    }
#pragma unroll
    for (int r = 0; r < 4; ++r) hid[(row0 + r) * 64 + lane] = to_xt<XT>(fmaxf(h2r[r], 0.f));
  }
}

template <typename XT>
__global__ __launch_bounds__(256) void k2_recur(
    const XT* __restrict__ hid, const int* __restrict__ done,
    const float* __restrict__ h0, const float* __restrict__ c0,
    const float* __restrict__ Wih, const float* __restrict__ Whh,
    const float* __restrict__ bl,
    const float* __restrict__ Wc1, const float* __restrict__ bc1,
    const float* __restrict__ Wc2, const float* __restrict__ bc2,
    const float* __restrict__ Wc3, const float* __restrict__ bc3,
    float* __restrict__ out) {
  __shared__ float sWih[64 * 256];
  __shared__ float sWhh[64 * 256];
  __shared__ float sbl[256];
  __shared__ float sWc1[64 * 16];
  __shared__ float sbc1[16];
  __shared__ float sWc2[16 * 8];
  __shared__ float sbc2[8];
  __shared__ float sWc3[8];
  __shared__ float hstage[4][4][68];

  int tid = threadIdx.x;
  for (int i = tid; i < 64 * 256; i += 256) {
    int k = i >> 8, r = i & 255, j = r >> 2, g = r & 3;
    sWih[i] = Wih[k * 256 + g * 64 + j];
    sWhh[i] = Whh[k * 256 + g * 64 + j];
  }
  for (int i = tid; i < 256; i += 256) {
    int j = i >> 2, g = i & 3;
    sbl[i] = bl[g * 64 + j];
  }
  for (int i = tid; i < 1024; i += 256) sWc1[i] = Wc1[i];
  if (tid < 128) sWc2[tid] = Wc2[tid];
  if (tid < 16) sbc1[tid] = bc1[tid];
  if (tid < 8) { sbc2[tid] = bc2[tid]; sWc3[tid] = Wc3[tid]; }
  __syncthreads();

  int lane = tid & 63;
  int wid = tid >> 6;
  int base_b = blockIdx.x * 16 + wid * 4;
  float bc3r = bc3[0];

  float h[4], c[4];
#pragma unroll
  for (int e = 0; e < 4; ++e) {
    h[e] = h0[(base_b + e) * 64 + lane];
    c[e] = c0[(base_b + e) * 64 + lane];
  }
  float hv[4];
  int dnv[4];
#pragma unroll
  for (int e = 0; e < 4; ++e) {
    hv[e] = from_xt(hid[(long)(base_b + e) * 64 + lane]);
    dnv[e] = done[base_b + e];
  }

  for (int t = 0; t < TT; ++t) {
    float hm[4], hd[4];
#pragma unroll
    for (int e = 0; e < 4; ++e) {
      float m = 1.f - (float)dnv[e];
      hm[e] = h[e] * m;
      c[e] *= m;
      hd[e] = hv[e];
    }
    if (t + 1 < TT) {
#pragma unroll
      for (int e = 0; e < 4; ++e) {
        long row = (long)(t + 1) * BB + base_b + e;
        hv[e] = from_xt(hid[row * 64 + lane]);
        dnv[e] = done[row];
      }
    }
    float4 acc[4];
#pragma unroll
    for (int e = 0; e < 4; ++e) acc[e] = ((const float4*)sbl)[lane];
#pragma unroll 16
    for (int k = 0; k < 64; ++k) {
      float4 wv = ((const float4*)sWih)[k * 64 + lane];
#pragma unroll
      for (int e = 0; e < 4; ++e) {
        float s = bcastf(hd[e], k);
        acc[e].x = fmaf(s, wv.x, acc[e].x);
        acc[e].y = fmaf(s, wv.y, acc[e].y);
        acc[e].z = fmaf(s, wv.z, acc[e].z);
        acc[e].w = fmaf(s, wv.w, acc[e].w);
      }
    }
#pragma unroll 16
    for (int k = 0; k < 64; ++k) {
      float4 wv = ((const float4*)sWhh)[k * 64 + lane];
#pragma unroll
      for (int e = 0; e < 4; ++e) {
        float s = bcastf(hm[e], k);
        acc[e].x = fmaf(s, wv.x, acc[e].x);
        acc[e].y = fmaf(s, wv.y, acc[e].y);
        acc[e].z = fmaf(s, wv.z, acc[e].z);
        acc[e].w = fmaf(s, wv.w, acc[e].w);
      }
    }
#pragma unroll
    for (int e = 0; e < 4; ++e) {
      float gi = fsig(acc[e].x);
      float gf = fsig(acc[e].y);
      float gg = ftanhf(acc[e].z);
      float go = fsig(acc[e].w);
      c[e] = fmaf(gf, c[e], gi * gg);
      h[e] = go * ftanhf(c[e]);
      hstage[wid][e][lane] = h[e];
    }
    __syncthreads();
    {
      int e2 = lane >> 4;
      int l16 = lane & 15;
      int gbase = lane & 48;
      const float* hrow = &hstage[wid][e2][0];
      float a1 = sbc1[l16];
#pragma unroll
      for (int k4 = 0; k4 < 16; ++k4) {
        float4 hh = *(const float4*)(hrow + k4 * 4);
        a1 = fmaf(hh.x, sWc1[(k4 * 4 + 0) * 16 + l16], a1);
        a1 = fmaf(hh.y, sWc1[(k4 * 4 + 1) * 16 + l16], a1);
        a1 = fmaf(hh.z, sWc1[(k4 * 4 + 2) * 16 + l16], a1);
        a1 = fmaf(hh.w, sWc1[(k4 * 4 + 3) * 16 + l16], a1);
      }
      float v1 = ftanhf(a1);
      float a2 = sbc2[lane & 7];
#pragma unroll
      for (int i = 0; i < 16; ++i)
        a2 = fmaf(__shfl(v1, gbase + i), sWc2[i * 8 + (lane & 7)], a2);
      float v2 = ftanhf(a2);
      float a3 = bc3r;
#pragma unroll
      for (int i = 0; i < 8; ++i)
        a3 = fmaf(__shfl(v2, gbase + i), sWc3[i], a3);
      if (l16 == 0) out[(long)t * BB + base_b + e2] = a3;
    }
    __syncthreads();
  }
}

extern "C" void kernel_launch(void* const* d_in, const int* in_sizes, int n_in,
                              void* d_out, int out_size, void* d_ws, size_t ws_size,
                              hipStream_t stream) {
  const float* x = (const float*)d_in[0];
  const int* done = (const int*)d_in[1];
  const float* h0 = (const float*)d_in[2];
  const float* c0 = (const float*)d_in[3];
  const float* Wr1 = (const float*)d_in[4];
  const float* br1 = (const float*)d_in[5];
  const float* Wr2 = (const float*)d_in[6];
  const float* br2 = (const float*)d_in[7];
  const float* Wih = (const float*)d_in[8];
  const float* Whh = (const float*)d_in[9];
  const float* bl = (const float*)d_in[10];
  const float* Wc1 = (const float*)d_in[11];
  const float* bc1 = (const float*)d_in[12];
  const float* Wc2 = (const float*)d_in[13];
  const float* bc2 = (const float*)d_in[14];
  const float* Wc3 = (const float*)d_in[15];
  const float* bc3 = (const float*)d_in[16];
  float* out = (float*)d_out;

  size_t xp_elems = (size_t)TBROWS * 256;
  size_t hs_elems = (size_t)TBROWS * 64;
  size_t need_fast = (xp_elems + hs_elems) * sizeof(float);  // ~1.34 GB
  size_t need_f32 = hs_elems * sizeof(float);                // 256 MB

  if (ws_size >= need_fast) {
    float* xp = (float*)d_ws;
    float* hs = (float*)d_ws + xp_elems;
    k1x<<<dim3(1024), dim3(256), 0, stream>>>(x, Wr1, br1, Wr2, br2, Wih, bl, xp);
    k2s<<<dim3(256), dim3(512), 0, stream>>>(xp, done, h0, c0, Whh, hs);
    kcrit<<<dim3(2048), dim3(256), 0, stream>>>(hs, Wc1, bc1, Wc2, bc2, Wc3, bc3, out);
  } else if (ws_size >= need_f32) {
    float* hid = (float*)d_ws;
    k1_mlp<float><<<dim3(2048), dim3(256), 0, stream>>>(x, Wr1, br1, Wr2, br2, hid);
    k2_recur<float><<<dim3(256), dim3(256), 0, stream>>>(hid, done, h0, c0, Wih, Whh, bl,
                                                         Wc1, bc1, Wc2, bc2, Wc3, bc3, out);
  } else {
    __hip_bfloat16* hid = (__hip_bfloat16*)d_ws;
    k1_mlp<__hip_bfloat16><<<dim3(2048), dim3(256), 0, stream>>>(x, Wr1, br1, Wr2, br2, hid);
    k2_recur<__hip_bfloat16><<<dim3(256), dim3(256), 0, stream>>>(hid, done, h0, c0, Wih, Whh, bl,
                                                                  Wc1, bc1, Wc2, bc2, Wc3, bc3, out);
  }
}

// Round 3
// 828.180 us; speedup vs baseline: 2.2417x; 2.2417x over previous
//
#include <hip/hip_runtime.h>
#include <hip/hip_bf16.h>

// T=256, B=4096, H=64.
// k1  : hid = relu(relu(x@Wr1+br1)@Wr2+br2) -> bf16 [T*B][64] in d_ws (128 MB)
// k2m : per-16-elem-tile serial LSTM, both matvecs via mfma_f32_16x16x32_bf16.
//       1 wave/block, 256 blocks, no barriers. Gate scales (log2e) folded into
//       staged B-fragments so sigmoid/tanh = exp2+rcp. hs overwrites hid
//       in-place (bf16, unit-permuted cols: pos p <-> unit 16*(p&3)+(p>>2)).
// kcrit: critic head over hs rows (permutation folded into sWc1 staging).

#define TT 256
#define BB 4096
#define TBROWS (TT * BB)
#define LOG2E 1.44269504088896340736f

typedef short bf16x8 __attribute__((ext_vector_type(8)));
typedef float f32x4 __attribute__((ext_vector_type(4)));

__device__ __forceinline__ float bcastf(float v, int i) {
  return __int_as_float(__builtin_amdgcn_readlane(__float_as_int(v), i));
}
__device__ __forceinline__ unsigned bfbits(float x) {  // f32 -> bf16 bits, RTNE
  unsigned u = __float_as_uint(x);
  return (u + 0x7fffu + ((u >> 16) & 1u)) >> 16;
}
__device__ __forceinline__ unsigned pkbf(float lo, float hi) {
  return bfbits(lo) | (bfbits(hi) << 16);
}
__device__ __forceinline__ float rcpf_(float x) { return __builtin_amdgcn_rcpf(x); }
__device__ __forceinline__ float exp2f_(float x) { return __builtin_amdgcn_exp2f(x); }
__device__ __forceinline__ float ftanhf(float x) { return 1.f - 2.f / (__expf(2.f * x) + 1.f); }

// ---------------- k1: root MLP -> bf16 hid ----------------
__global__ __launch_bounds__(256) void k1(const float* __restrict__ x,
                                          const float* __restrict__ Wr1,
                                          const float* __restrict__ br1,
                                          const float* __restrict__ Wr2,
                                          const float* __restrict__ br2,
                                          unsigned short* __restrict__ hb) {
  __shared__ float sWr1[9 * 32];
  __shared__ float sbr1[32];
  __shared__ float sWr2[32 * 64];
  __shared__ float sbr2[64];
  int tid = threadIdx.x;
  for (int i = tid; i < 288; i += 256) sWr1[i] = Wr1[i];
  if (tid < 32) sbr1[tid] = br1[tid];
  for (int i = tid; i < 2048; i += 256) sWr2[i] = Wr2[i];
  if (tid < 64) sbr2[tid] = br2[tid];
  __syncthreads();

  int lane = tid & 63;
  int wid = tid >> 6;
  int l = lane & 31;
  long gw = (long)blockIdx.x * 4 + wid;
  long nw = (long)gridDim.x * 4;
  for (long row0 = gw * 4; row0 < TBROWS; row0 += nw * 4) {
    float xl = 0.f;
    if (lane < 36) xl = x[row0 * 9 + lane];
    float h1r[4];
#pragma unroll
    for (int r = 0; r < 4; ++r) {
      float a = sbr1[l];
#pragma unroll
      for (int k = 0; k < 9; ++k) a = fmaf(bcastf(xl, r * 9 + k), sWr1[k * 32 + l], a);
      h1r[r] = fmaxf(a, 0.f);
    }
    float h2r[4];
#pragma unroll
    for (int r = 0; r < 4; ++r) h2r[r] = sbr2[lane];
#pragma unroll
    for (int i = 0; i < 32; ++i) {
      float w = sWr2[i * 64 + lane];
#pragma unroll
      for (int r = 0; r < 4; ++r) h2r[r] = fmaf(bcastf(h1r[r], i), w, h2r[r]);
    }
#pragma unroll
    for (int r = 0; r < 4; ++r)
      hb[(row0 + r) * 64 + lane] = (unsigned short)bfbits(fmaxf(h2r[r], 0.f));
  }
}

// ---------------- k2m: MFMA serial LSTM ----------------
// block = 64 threads (1 wave), grid = 256 blocks; block b owns elems [16b,16b+16).
// acc/C layout (m89): col = lane&15, row = (lane>>4)*4 + reg.
// col = nt*16 + (lane&15); gate = nt>>2, unit j = (nt&3)*16 + (lane&15).
__global__ __launch_bounds__(64) void k2m(
    unsigned short* __restrict__ hb,  // in: hid bf16; out: hs (in-place)
    const int* __restrict__ done,
    const float* __restrict__ h0, const float* __restrict__ c0,
    const float* __restrict__ Wih, const float* __restrict__ Whh,
    const float* __restrict__ bl) {
  __shared__ int sBih[8192];           // 16 nt x 2 q x 64 lanes x 4 dwords
  __shared__ int sBhh[8192];
  __shared__ unsigned short hT[64 * 20];  // [unit][elem], stride 20 to spread banks

  const int lane = threadIdx.x;
  const int g4 = lane >> 4, l15 = lane & 15;
  const int base_b = blockIdx.x * 16;

  // Stage B fragments. k-order formula identical to A-side builds below, so any
  // HW (lane,dword,half)->k mapping contracts correctly. Gate scales folded in.
  for (int dwi = lane; dwi < 8192; dwi += 64) {
    int f = dwi >> 8, rem = dwi & 255;
    int L = rem >> 2, dd = rem & 3;
    int nt = f >> 1, q = f & 1;
    int k0 = q * 32 + (L >> 4) * 8 + 2 * dd;
    int col = nt * 16 + (L & 15);
    float sc = ((nt >> 2) == 2) ? 2.f * LOG2E : LOG2E;
    sBih[dwi] = (int)pkbf(Wih[k0 * 256 + col] * sc, Wih[(k0 + 1) * 256 + col] * sc);
    sBhh[dwi] = (int)pkbf(Whh[k0 * 256 + col] * sc, Whh[(k0 + 1) * 256 + col] * sc);
  }
  float bias16[16];
#pragma unroll
  for (int nt = 0; nt < 16; ++nt) {
    float sc = ((nt >> 2) == 2) ? 2.f * LOG2E : LOG2E;
    bias16[nt] = bl[nt * 16 + l15] * sc;
  }
  __syncthreads();

  // h0/c0 into C-layout, apply m0
  float c[4][4], h0v[4][4], m0[4];
#pragma unroll
  for (int b = 0; b < 4; ++b)
#pragma unroll
    for (int r = 0; r < 4; ++r) {
      int row = base_b + g4 * 4 + r;
      h0v[b][r] = h0[row * 64 + b * 16 + l15];
      c[b][r] = c0[row * 64 + b * 16 + l15];
    }
#pragma unroll
  for (int r = 0; r < 4; ++r) m0[r] = 1.f - (float)done[base_b + g4 * 4 + r];
#pragma unroll
  for (int b = 0; b < 4; ++b)
#pragma unroll
    for (int r = 0; r < 4; ++r) c[b][r] *= m0[r];
#pragma unroll
  for (int b = 0; b < 4; ++b) {
    unsigned p0 = pkbf(h0v[b][0] * m0[0], h0v[b][1] * m0[1]);
    unsigned p1 = pkbf(h0v[b][2] * m0[2], h0v[b][3] * m0[3]);
    *(uint2*)&hT[(b * 16 + l15) * 20 + g4 * 4] = make_uint2(p0, p1);
  }

  // A_ih for t=0 (row-major bf16 hid: lane -> row l15, units q*32+g4*8..+7)
  long tb0 = (long)base_b * 64;
  bf16x8 aih0 = *(const bf16x8*)(hb + tb0 + l15 * 64 + g4 * 8);
  bf16x8 aih1 = *(const bf16x8*)(hb + tb0 + l15 * 64 + 32 + g4 * 8);

  float out_h[4][4];
  for (int t = 0; t < TT; ++t) {
    // prefetch next-step inputs
    bf16x8 nx0 = aih0, nx1 = aih1;
    int dnx[4] = {0, 0, 0, 0};
    if (t + 1 < TT) {
      long nb = ((long)(t + 1) * BB + base_b) * 64;
      nx0 = *(const bf16x8*)(hb + nb + l15 * 64 + g4 * 8);
      nx1 = *(const bf16x8*)(hb + nb + l15 * 64 + 32 + g4 * 8);
#pragma unroll
      for (int r = 0; r < 4; ++r) dnx[r] = done[(long)(t + 1) * BB + base_b + g4 * 4 + r];
    }
    // A_hh from hT (units = same k-order formula as sBhh staging)
    union { int i[4]; bf16x8 v; } ah0, ah1;
#pragma unroll
    for (int d = 0; d < 4; ++d) {
      int u0 = g4 * 8 + 2 * d;
      ah0.i[d] = (int)((unsigned)hT[u0 * 20 + l15] | ((unsigned)hT[(u0 + 1) * 20 + l15] << 16));
      int u1 = 32 + u0;
      ah1.i[d] = (int)((unsigned)hT[u1 * 20 + l15] | ((unsigned)hT[(u1 + 1) * 20 + l15] << 16));
    }
    f32x4 acc[16];
#pragma unroll
    for (int nt = 0; nt < 16; ++nt) {
      float bv = bias16[nt];
      acc[nt] = (f32x4){bv, bv, bv, bv};
    }
#pragma unroll
    for (int nt = 0; nt < 16; ++nt)
      acc[nt] = __builtin_amdgcn_mfma_f32_16x16x32_bf16(
          aih0, *(const bf16x8*)&sBih[(nt * 2 + 0) * 256 + lane * 4], acc[nt], 0, 0, 0);
#pragma unroll
    for (int nt = 0; nt < 16; ++nt)
      acc[nt] = __builtin_amdgcn_mfma_f32_16x16x32_bf16(
          aih1, *(const bf16x8*)&sBih[(nt * 2 + 1) * 256 + lane * 4], acc[nt], 0, 0, 0);
#pragma unroll
    for (int nt = 0; nt < 16; ++nt)
      acc[nt] = __builtin_amdgcn_mfma_f32_16x16x32_bf16(
          ah0.v, *(const bf16x8*)&sBhh[(nt * 2 + 0) * 256 + lane * 4], acc[nt], 0, 0, 0);
#pragma unroll
    for (int nt = 0; nt < 16; ++nt)
      acc[nt] = __builtin_amdgcn_mfma_f32_16x16x32_bf16(
          ah1.v, *(const bf16x8*)&sBhh[(nt * 2 + 1) * 256 + lane * 4], acc[nt], 0, 0, 0);

    // elementwise: acc already scaled by log2e (2*log2e for g-gate)
#pragma unroll
    for (int b = 0; b < 4; ++b)
#pragma unroll
      for (int r = 0; r < 4; ++r) {
        float xi = acc[b][r], xf = acc[4 + b][r], xg = acc[8 + b][r], xo = acc[12 + b][r];
        float si = rcpf_(1.f + exp2f_(-xi));
        float sf = rcpf_(1.f + exp2f_(-xf));
        float so = rcpf_(1.f + exp2f_(-xo));
        float tg = fmaf(2.f, rcpf_(1.f + exp2f_(-xg)), -1.f);
        float cc = fmaf(sf, c[b][r], si * tg);
        c[b][r] = cc;
        float tc = fmaf(2.f, rcpf_(1.f + exp2f_(cc * (-2.f * LOG2E))), -1.f);
        out_h[b][r] = so * tc;
      }

    // hs store (unmasked h_t), in-place over hid, permuted cols: pos l15*4+b
    long rowbase = ((long)t * BB + base_b + g4 * 4) * 64;
#pragma unroll
    for (int r = 0; r < 4; ++r) {
      uint2 w;
      w.x = pkbf(out_h[0][r], out_h[1][r]);
      w.y = pkbf(out_h[2][r], out_h[3][r]);
      *(uint2*)(hb + rowbase + (long)r * 64 + l15 * 4) = w;
    }

    if (t + 1 < TT) {
      float mn[4];
#pragma unroll
      for (int r = 0; r < 4; ++r) mn[r] = 1.f - (float)dnx[r];
#pragma unroll
      for (int b = 0; b < 4; ++b) {
        unsigned p0 = pkbf(out_h[b][0] * mn[0], out_h[b][1] * mn[1]);
        unsigned p1 = pkbf(out_h[b][2] * mn[2], out_h[b][3] * mn[3]);
        *(uint2*)&hT[(b * 16 + l15) * 20 + g4 * 4] = make_uint2(p0, p1);
      }
#pragma unroll
      for (int b = 0; b < 4; ++b)
#pragma unroll
        for (int r = 0; r < 4; ++r) c[b][r] *= mn[r];
      aih0 = nx0;
      aih1 = nx1;
    }
  }
}

// ---------------- kcrit: critic head over bf16 hs ----------------
__global__ __launch_bounds__(256) void kcrit(const unsigned short* __restrict__ hb,
                                             const float* __restrict__ Wc1,
                                             const float* __restrict__ bc1,
                                             const float* __restrict__ Wc2,
                                             const float* __restrict__ bc2,
                                             const float* __restrict__ Wc3,
                                             const float* __restrict__ bc3,
                                             float* __restrict__ out) {
  __shared__ float sWc1[64 * 16];  // permuted: row p holds Wc1 row 16*(p&3)+(p>>2)
  __shared__ float sbc1[16];
  __shared__ float sWc2[16 * 8];
  __shared__ float sbc2[8];
  __shared__ float sWc3[8];
  __shared__ float hstage[4][4][68];
  int tid = threadIdx.x;
  for (int i = tid; i < 1024; i += 256) {
    int p = i >> 4, o = i & 15;
    int u = (p & 3) * 16 + (p >> 2);
    sWc1[i] = Wc1[u * 16 + o];
  }
  if (tid < 128) sWc2[tid] = Wc2[tid];
  if (tid < 16) sbc1[tid] = bc1[tid];
  if (tid < 8) { sbc2[tid] = bc2[tid]; sWc3[tid] = Wc3[tid]; }
  __syncthreads();

  int lane = tid & 63;
  int wid = tid >> 6;
  float bc3r = bc3[0];
  int e2 = lane >> 4;
  int l16 = lane & 15;
  int gbase = lane & 48;
  long gw = (long)blockIdx.x * 4 + wid;
  long nw = (long)gridDim.x * 4;
  for (long row0 = gw * 4; row0 < TBROWS; row0 += nw * 4) {
    uint2 hv = *(const uint2*)(hb + (row0 + e2) * 64 + l16 * 4);
    float4 hf;
    hf.x = __uint_as_float(hv.x << 16);
    hf.y = __uint_as_float(hv.x & 0xffff0000u);
    hf.z = __uint_as_float(hv.y << 16);
    hf.w = __uint_as_float(hv.y & 0xffff0000u);
    *(float4*)&hstage[wid][e2][l16 * 4] = hf;  // wave-local staging
    const float* hrow = &hstage[wid][e2][0];
    float a1 = sbc1[l16];
#pragma unroll
    for (int k4 = 0; k4 < 16; ++k4) {
      float4 hh = *(const float4*)(hrow + k4 * 4);
      a1 = fmaf(hh.x, sWc1[(k4 * 4 + 0) * 16 + l16], a1);
      a1 = fmaf(hh.y, sWc1[(k4 * 4 + 1) * 16 + l16], a1);
      a1 = fmaf(hh.z, sWc1[(k4 * 4 + 2) * 16 + l16], a1);
      a1 = fmaf(hh.w, sWc1[(k4 * 4 + 3) * 16 + l16], a1);
    }
    float v1 = ftanhf(a1);
    float a2 = sbc2[lane & 7];
#pragma unroll
    for (int i = 0; i < 16; ++i)
      a2 = fmaf(__shfl(v1, gbase + i), sWc2[i * 8 + (lane & 7)], a2);
    float v2 = ftanhf(a2);
    float a3 = bc3r;
#pragma unroll
    for (int i = 0; i < 8; ++i)
      a3 = fmaf(__shfl(v2, gbase + i), sWc3[i], a3);
    if (l16 == 0) out[row0 + e2] = a3;
  }
}

extern "C" void kernel_launch(void* const* d_in, const int* in_sizes, int n_in,
                              void* d_out, int out_size, void* d_ws, size_t ws_size,
                              hipStream_t stream) {
  const float* x = (const float*)d_in[0];
  const int* done = (const int*)d_in[1];
  const float* h0 = (const float*)d_in[2];
  const float* c0 = (const float*)d_in[3];
  const float* Wr1 = (const float*)d_in[4];
  const float* br1 = (const float*)d_in[5];
  const float* Wr2 = (const float*)d_in[6];
  const float* br2 = (const float*)d_in[7];
  const float* Wih = (const float*)d_in[8];
  const float* Whh = (const float*)d_in[9];
  const float* bl = (const float*)d_in[10];
  const float* Wc1 = (const float*)d_in[11];
  const float* bc1 = (const float*)d_in[12];
  const float* Wc2 = (const float*)d_in[13];
  const float* bc2 = (const float*)d_in[14];
  const float* Wc3 = (const float*)d_in[15];
  const float* bc3 = (const float*)d_in[16];
  float* out = (float*)d_out;

  unsigned short* hb = (unsigned short*)d_ws;  // 128 MB bf16, hid then hs in-place

  k1<<<dim3(2048), dim3(256), 0, stream>>>(x, Wr1, br1, Wr2, br2, hb);
  k2m<<<dim3(256), dim3(64), 0, stream>>>(hb, done, h0, c0, Wih, Whh, bl);
  kcrit<<<dim3(2048), dim3(256), 0, stream>>>(hb, Wc1, bc1, Wc2, bc2, Wc3, bc3, out);
}

// Round 4
// 456.525 us; speedup vs baseline: 4.0666x; 1.8141x over previous
//
#include <hip/hip_runtime.h>
#include <hip/hip_bf16.h>

// T=256, B=4096, H=64.
// k1  : hid = relu(relu(x@Wr1+br1)@Wr2+br2) -> bf16 [T*B][64] in d_ws (128 MB, read-only after)
// k2m : block = 16 batch elems, 320 threads (5 waves), 256 blocks.
//   waves 0-3: gate wave w computes units [16w,16w+16) x 4 gates = 16 MFMAs/step
//              (mfma_f32_16x16x32_bf16), h exchanged via LDS hT2[elem][unit]
//              (unmasked bf16; done-mask applied as v_cndmask at A-fragment build).
//   wave 4   : critic head of h_{t-1} (pipelined), Wc1 via 2 MFMAs, Wc2/Wc3 via
//              VALU + LDS bounce, writes out[t-1]. Tail handles t=255.
//   2 barriers/step. No hs in global memory at all.

#define TT 256
#define BB 4096
#define TBROWS (TT * BB)
#define LOG2E 1.44269504088896340736f

typedef short bf16x8 __attribute__((ext_vector_type(8)));
typedef float f32x4 __attribute__((ext_vector_type(4)));

__device__ __forceinline__ float bcastf(float v, int i) {
  return __int_as_float(__builtin_amdgcn_readlane(__float_as_int(v), i));
}
__device__ __forceinline__ unsigned bfbits(float x) {  // f32 -> bf16 bits, RTNE
  unsigned u = __float_as_uint(x);
  return (u + 0x7fffu + ((u >> 16) & 1u)) >> 16;
}
__device__ __forceinline__ unsigned pkbf(float lo, float hi) {
  return bfbits(lo) | (bfbits(hi) << 16);
}
__device__ __forceinline__ float rcpf_(float x) { return __builtin_amdgcn_rcpf(x); }
__device__ __forceinline__ float exp2f_(float x) { return __builtin_amdgcn_exp2f(x); }

// ---------------- k1: root MLP -> bf16 hid ----------------
__global__ __launch_bounds__(256) void k1(const float* __restrict__ x,
                                          const float* __restrict__ Wr1,
                                          const float* __restrict__ br1,
                                          const float* __restrict__ Wr2,
                                          const float* __restrict__ br2,
                                          unsigned short* __restrict__ hb) {
  __shared__ float sWr1[9 * 32];
  __shared__ float sbr1[32];
  __shared__ float sWr2[32 * 64];
  __shared__ float sbr2[64];
  int tid = threadIdx.x;
  for (int i = tid; i < 288; i += 256) sWr1[i] = Wr1[i];
  if (tid < 32) sbr1[tid] = br1[tid];
  for (int i = tid; i < 2048; i += 256) sWr2[i] = Wr2[i];
  if (tid < 64) sbr2[tid] = br2[tid];
  __syncthreads();

  int lane = tid & 63;
  int wid = tid >> 6;
  int l = lane & 31;
  long gw = (long)blockIdx.x * 4 + wid;
  long nw = (long)gridDim.x * 4;
  for (long row0 = gw * 4; row0 < TBROWS; row0 += nw * 4) {
    float xl = 0.f;
    if (lane < 36) xl = x[row0 * 9 + lane];
    float h1r[4];
#pragma unroll
    for (int r = 0; r < 4; ++r) {
      float a = sbr1[l];
#pragma unroll
      for (int k = 0; k < 9; ++k) a = fmaf(bcastf(xl, r * 9 + k), sWr1[k * 32 + l], a);
      h1r[r] = fmaxf(a, 0.f);
    }
    float h2r[4];
#pragma unroll
    for (int r = 0; r < 4; ++r) h2r[r] = sbr2[lane];
#pragma unroll
    for (int i = 0; i < 32; ++i) {
      float w = sWr2[i * 64 + lane];
#pragma unroll
      for (int r = 0; r < 4; ++r) h2r[r] = fmaf(bcastf(h1r[r], i), w, h2r[r]);
    }
#pragma unroll
    for (int r = 0; r < 4; ++r)
      hb[(row0 + r) * 64 + lane] = (unsigned short)bfbits(fmaxf(h2r[r], 0.f));
  }
}

// ---------------- k2m: MFMA serial LSTM, column-split + critic wave ----------------
// C layout (m89): col = lane&15, row = (lane>>4)*4 + reg.
// Gate wave w: nt = g*4+w -> unit j = 16w + (lane&15), gate g; rows (lane>>4)*4+r.
__global__ __launch_bounds__(320) void k2m(
    const unsigned short* __restrict__ hb, const int* __restrict__ done,
    const float* __restrict__ h0, const float* __restrict__ c0,
    const float* __restrict__ Wih, const float* __restrict__ Whh,
    const float* __restrict__ bl,
    const float* __restrict__ Wc1, const float* __restrict__ bc1,
    const float* __restrict__ Wc2, const float* __restrict__ bc2,
    const float* __restrict__ Wc3, const float* __restrict__ bc3,
    float* __restrict__ out) {
  __shared__ int sBih[8192];      // 16 nt x 2 q x 64 lanes x 4 dwords (bf16 pairs)
  __shared__ int sBhh[8192];
  __shared__ int sBc1[512];       // 2 q x 64 lanes x 4 dwords, scaled 2*log2e
  __shared__ __align__(16) unsigned short hT2[16 * 72];  // [elem][unit], unmasked h
  __shared__ float sv1[16 * 20];  // critic v1 bounce [row][col]
  __shared__ float sWc2[16 * 8];  // scaled 2*log2e

  const int tid = threadIdx.x;
  const int lane = tid & 63;
  const int wid = tid >> 6;
  const int g4 = lane >> 4, l15 = lane & 15;
  const int base_b = blockIdx.x * 16;

  // ---- stage weights (all 320 threads) ----
  for (int dwi = tid; dwi < 8192; dwi += 320) {
    int f = dwi >> 8, rem = dwi & 255;
    int L = rem >> 2, dd = rem & 3;
    int nt = f >> 1, q = f & 1;
    int k0 = q * 32 + (L >> 4) * 8 + 2 * dd;
    int col = nt * 16 + (L & 15);
    float sc = ((nt >> 2) == 2) ? 2.f * LOG2E : LOG2E;
    sBih[dwi] = (int)pkbf(Wih[k0 * 256 + col] * sc, Wih[(k0 + 1) * 256 + col] * sc);
    sBhh[dwi] = (int)pkbf(Whh[k0 * 256 + col] * sc, Whh[(k0 + 1) * 256 + col] * sc);
  }
  for (int dwi = tid; dwi < 512; dwi += 320) {
    int q = dwi >> 8, rem = dwi & 255;
    int L = rem >> 2, dd = rem & 3;
    int k0 = q * 32 + (L >> 4) * 8 + 2 * dd;
    int col = L & 15;
    float S = 2.f * LOG2E;
    sBc1[dwi] = (int)pkbf(Wc1[k0 * 16 + col] * S, Wc1[(k0 + 1) * 16 + col] * S);
  }
  for (int i = tid; i < 128; i += 320) sWc2[i] = Wc2[i] * 2.f * LOG2E;

  // ---- init state ----
  float c[4];        // gate waves: c for unit 16w+l15, rows g4*4+r
  float bias_g[4];   // gate waves: bias per gate (scaled)
  if (wid < 4) {
#pragma unroll
    for (int g = 0; g < 4; ++g) {
      float sc = (g == 2) ? 2.f * LOG2E : LOG2E;
      bias_g[g] = bl[(g * 4 + wid) * 16 + l15] * sc;
    }
#pragma unroll
    for (int r = 0; r < 4; ++r) {
      int row = base_b + g4 * 4 + r;
      float m0 = 1.f - (float)done[row];
      c[r] = c0[row * 64 + wid * 16 + l15] * m0;
      // h0 (UNMASKED) into hT2; mask applied at A-build via cndmask
      hT2[(g4 * 4 + r) * 72 + wid * 16 + l15] =
          (unsigned short)bfbits(h0[row * 64 + wid * 16 + l15]);
    }
  }
  float bc1s = 0.f, bc2s0 = 0.f, bc2s1 = 0.f, wc3a = 0.f, wc3b = 0.f, bc3r = 0.f;
  if (wid == 4) {
    bc1s = bc1[l15] * 2.f * LOG2E;
    bc2s0 = bc2[g4 * 2] * 2.f * LOG2E;
    bc2s1 = bc2[g4 * 2 + 1] * 2.f * LOG2E;
    wc3a = Wc3[g4 * 2];
    wc3b = Wc3[g4 * 2 + 1];
    bc3r = bc3[0];
  }
  __syncthreads();

  // ---- gate-wave loop-carried inputs ----
  bf16x8 aih0 = {}, aih1 = {};
  int dn_a = 0, dnc[4] = {0, 0, 0, 0};
  const bf16x8* pB[4][4];  // [gate][frag: ih_q0, ih_q1, hh_q0, hh_q1]
  if (wid < 4) {
    long tb0 = (long)base_b * 64;
    aih0 = *(const bf16x8*)(hb + tb0 + l15 * 64 + g4 * 8);
    aih1 = *(const bf16x8*)(hb + tb0 + l15 * 64 + 32 + g4 * 8);
    dn_a = done[base_b + l15];
#pragma unroll
    for (int g = 0; g < 4; ++g) {
      int nt = g * 4 + wid;
      pB[g][0] = (const bf16x8*)&sBih[(nt * 2 + 0) * 256 + lane * 4];
      pB[g][1] = (const bf16x8*)&sBih[(nt * 2 + 1) * 256 + lane * 4];
      pB[g][2] = (const bf16x8*)&sBhh[(nt * 2 + 0) * 256 + lane * 4];
      pB[g][3] = (const bf16x8*)&sBhh[(nt * 2 + 1) * 256 + lane * 4];
    }
  }

  // ---- critic body: head(h_tprev) from hT2 -> out[tprev] ----
  auto critic_step = [&](int tprev) {
    bf16x8 ca0 = *(const bf16x8*)&hT2[l15 * 72 + g4 * 8];
    bf16x8 ca1 = *(const bf16x8*)&hT2[l15 * 72 + 32 + g4 * 8];
    f32x4 a1 = (f32x4){bc1s, bc1s, bc1s, bc1s};
    a1 = __builtin_amdgcn_mfma_f32_16x16x32_bf16(ca0, *(const bf16x8*)&sBc1[0 * 256 + lane * 4], a1, 0, 0, 0);
    a1 = __builtin_amdgcn_mfma_f32_16x16x32_bf16(ca1, *(const bf16x8*)&sBc1[1 * 256 + lane * 4], a1, 0, 0, 0);
#pragma unroll
    for (int r = 0; r < 4; ++r) {
      float v1 = fmaf(2.f, rcpf_(1.f + exp2f_(-a1[r])), -1.f);
      sv1[(g4 * 4 + r) * 20 + l15] = v1;  // [row][col]
    }
    // v2: lane (g4,l15) -> row l15, cols {2g4, 2g4+1}
    float a2a = bc2s0, a2b = bc2s1;
    const float* vrow = &sv1[l15 * 20];
#pragma unroll
    for (int k = 0; k < 16; ++k) {
      float vk = vrow[k];
      a2a = fmaf(vk, sWc2[k * 8 + g4 * 2], a2a);
      a2b = fmaf(vk, sWc2[k * 8 + g4 * 2 + 1], a2b);
    }
    float v2a = fmaf(2.f, rcpf_(1.f + exp2f_(-a2a)), -1.f);
    float v2b = fmaf(2.f, rcpf_(1.f + exp2f_(-a2b)), -1.f);
    float p = fmaf(v2a, wc3a, v2b * wc3b);
    p += __shfl_xor(p, 16);
    p += __shfl_xor(p, 32);
    if (g4 == 0) out[(long)tprev * BB + base_b + l15] = p + bc3r;
  };

  // ---- main serial loop ----
  for (int t = 0; t < TT; ++t) {
    if (wid < 4) {
      // A_hh from hT2 (h_{t-1}, unmasked) with cndmask reset for done[t]
      int4 r0 = *(const int4*)&hT2[l15 * 72 + g4 * 8];
      int4 r1 = *(const int4*)&hT2[l15 * 72 + 32 + g4 * 8];
      if (dn_a != 0) { r0 = make_int4(0, 0, 0, 0); r1 = make_int4(0, 0, 0, 0); }
      union { int4 i4; bf16x8 v; } ah0, ah1;
      ah0.i4 = r0; ah1.i4 = r1;

      // prefetch t+1 inputs
      bf16x8 nx0 = aih0, nx1 = aih1;
      int dn_a_nx = 0, dnc_nx[4] = {0, 0, 0, 0};
      if (t + 1 < TT) {
        long nb = ((long)(t + 1) * BB + base_b) * 64;
        nx0 = *(const bf16x8*)(hb + nb + l15 * 64 + g4 * 8);
        nx1 = *(const bf16x8*)(hb + nb + l15 * 64 + 32 + g4 * 8);
        dn_a_nx = done[(long)(t + 1) * BB + base_b + l15];
#pragma unroll
        for (int r = 0; r < 4; ++r)
          dnc_nx[r] = done[(long)(t + 1) * BB + base_b + g4 * 4 + r];
      }

      f32x4 acc[4];
#pragma unroll
      for (int g = 0; g < 4; ++g)
        acc[g] = (f32x4){bias_g[g], bias_g[g], bias_g[g], bias_g[g]};
#pragma unroll
      for (int g = 0; g < 4; ++g)
        acc[g] = __builtin_amdgcn_mfma_f32_16x16x32_bf16(aih0, *pB[g][0], acc[g], 0, 0, 0);
#pragma unroll
      for (int g = 0; g < 4; ++g)
        acc[g] = __builtin_amdgcn_mfma_f32_16x16x32_bf16(aih1, *pB[g][1], acc[g], 0, 0, 0);
#pragma unroll
      for (int g = 0; g < 4; ++g)
        acc[g] = __builtin_amdgcn_mfma_f32_16x16x32_bf16(ah0.v, *pB[g][2], acc[g], 0, 0, 0);
#pragma unroll
      for (int g = 0; g < 4; ++g)
        acc[g] = __builtin_amdgcn_mfma_f32_16x16x32_bf16(ah1.v, *pB[g][3], acc[g], 0, 0, 0);

      float out_h[4];
#pragma unroll
      for (int r = 0; r < 4; ++r) {
        float xi = acc[0][r], xf = acc[1][r], xg = acc[2][r], xo = acc[3][r];
        float si = rcpf_(1.f + exp2f_(-xi));
        float sf = rcpf_(1.f + exp2f_(-xf));
        float so = rcpf_(1.f + exp2f_(-xo));
        float tg = fmaf(2.f, rcpf_(1.f + exp2f_(-xg)), -1.f);
        float cc = fmaf(sf, c[r], si * tg);
        float tc = fmaf(2.f, rcpf_(1.f + exp2f_(cc * (-2.f * LOG2E))), -1.f);
        out_h[r] = so * tc;
        c[r] = cc * (1.f - (float)dnc_nx[r]);  // mask for t+1
      }

      __syncthreads();  // barrier 1: everyone done reading hT2
#pragma unroll
      for (int r = 0; r < 4; ++r)
        hT2[(g4 * 4 + r) * 72 + wid * 16 + l15] = (unsigned short)bfbits(out_h[r]);
      __syncthreads();  // barrier 2: hT2 = h_t visible

      aih0 = nx0; aih1 = nx1; dn_a = dn_a_nx;
    } else {
      if (t > 0) critic_step(t - 1);
      __syncthreads();  // barrier 1
      __syncthreads();  // barrier 2
    }
  }
  if (wid == 4) critic_step(TT - 1);
}

extern "C" void kernel_launch(void* const* d_in, const int* in_sizes, int n_in,
                              void* d_out, int out_size, void* d_ws, size_t ws_size,
                              hipStream_t stream) {
  const float* x = (const float*)d_in[0];
  const int* done = (const int*)d_in[1];
  const float* h0 = (const float*)d_in[2];
  const float* c0 = (const float*)d_in[3];
  const float* Wr1 = (const float*)d_in[4];
  const float* br1 = (const float*)d_in[5];
  const float* Wr2 = (const float*)d_in[6];
  const float* br2 = (const float*)d_in[7];
  const float* Wih = (const float*)d_in[8];
  const float* Whh = (const float*)d_in[9];
  const float* bl = (const float*)d_in[10];
  const float* Wc1 = (const float*)d_in[11];
  const float* bc1 = (const float*)d_in[12];
  const float* Wc2 = (const float*)d_in[13];
  const float* bc2 = (const float*)d_in[14];
  const float* Wc3 = (const float*)d_in[15];
  const float* bc3 = (const float*)d_in[16];
  float* out = (float*)d_out;

  unsigned short* hb = (unsigned short*)d_ws;  // 128 MB bf16 hid (read-only after k1)

  k1<<<dim3(2048), dim3(256), 0, stream>>>(x, Wr1, br1, Wr2, br2, hb);
  k2m<<<dim3(256), dim3(320), 0, stream>>>(hb, done, h0, c0, Wih, Whh, bl,
                                           Wc1, bc1, Wc2, bc2, Wc3, bc3, out);
}